// Round 9
// baseline (584.784 us; speedup 1.0000x reference)
//
#include <hip/hip_runtime.h>
#include <math.h>
#include <stddef.h>

#define NLAYER 24
#define NEMBD  1024
#define NFFN   4096
#define NB     256
#define NT     256
#define LN_EPS 1e-5f

#define OUT_SA (NEMBD)
#define OUT_SB (NEMBD + NLAYER*NEMBD)
#define OUT_SC (NEMBD + 2*NLAYER*NEMBD)
#define OUT_SD (NEMBD + 3*NLAYER*NEMBD)

#define FLAG_STRIDE 32   // 32 u32 = 128 B per block flag line

struct Params {
  const float *x, *state, *ln1w, *ln1b, *ln2w, *ln2b, *td, *tf, *kktk, *vvtv, *rrtr;
  const float *key, *outputv, *tmk, *tmr, *kffn, *rffn, *vffn;
  float *out;
  float *xbuf, *kvr, *sxx, *rfb, *kfb;
  unsigned *flags;
};

__device__ __forceinline__ float wred(float v) {
#pragma unroll
  for (int o = 32; o > 0; o >>= 1) v += __shfl_xor(v, o, 64);
  return v;
}
__device__ __forceinline__ float dot4(float4 a, float4 b) {
  return a.x*b.x + a.y*b.y + a.z*b.z + a.w*b.w;
}
__device__ __forceinline__ float fcomp(float4 v, int j) {   // literal j only
  return j == 0 ? v.x : (j == 1 ? v.y : (j == 2 ? v.z : v.w));
}
// relaxed agent-scope ops -> sc0/sc1 global ops through the LLC; no wbl2/inv
__device__ __forceinline__ float gload(const float* a) {
  return __hip_atomic_load(a, __ATOMIC_RELAXED, __HIP_MEMORY_SCOPE_AGENT);
}
__device__ __forceinline__ void gstore(float* a, float v) {
  __hip_atomic_store(a, v, __ATOMIC_RELAXED, __HIP_MEMORY_SCOPE_AGENT);
}
__device__ __forceinline__ unsigned guload(const unsigned* a) {
  return __hip_atomic_load(a, __ATOMIC_RELAXED, __HIP_MEMORY_SCOPE_AGENT);
}
__device__ __forceinline__ void gustore(unsigned* a, unsigned v) {
  __hip_atomic_store(a, v, __ATOMIC_RELAXED, __HIP_MEMORY_SCOPE_AGENT);
}

// intra-stage barrier: LDS ordering only (lgkmcnt); global prefetch stays in flight
__device__ __forceinline__ void lbar() {
  __builtin_amdgcn_sched_barrier(0);
  asm volatile("s_waitcnt lgkmcnt(0)" ::: "memory");
  __builtin_amdgcn_s_barrier();
  asm volatile("" ::: "memory");
  __builtin_amdgcn_sched_barrier(0);
}

// arrive: __syncthreads drains this block's result gstores (vmcnt 0 at this
// point holds ONLY stores -- all prefetch was consumed by the dots), then
// thread 0 publishes flag[b]=tgt.
__device__ __forceinline__ void bar_flag(unsigned* flags, unsigned tgt) {
  __syncthreads();
  if (threadIdx.x == 0) {
    gustore(&flags[(unsigned)blockIdx.x * FLAG_STRIDE], tgt);
  }
}

// FASTPOLL: issue 4 flag loads (asm, untracked by compiler), then the whole
// next-stage prefetch, then wait vmcnt(EXACT prefetch count) -- retires only
// the 4 poll loads (in-order). Last-arriving block sees all flags set and
// crosses the barrier with zero drain; early blocks fall into the slow spin.
#define FASTPOLL(NSTR, PFSTMT)                                               \
  do {                                                                       \
    unsigned f0_, f1_, f2_, f3_;                                             \
    const unsigned* fp_ = p.flags + (unsigned)lane * 4u * FLAG_STRIDE;       \
    asm volatile(                                                            \
      "global_load_dword %0, %4, off sc0 sc1\n\t"                            \
      "global_load_dword %1, %4, off offset:128 sc0 sc1\n\t"                 \
      "global_load_dword %2, %4, off offset:256 sc0 sc1\n\t"                 \
      "global_load_dword %3, %4, off offset:384 sc0 sc1"                     \
      : "=v"(f0_), "=v"(f1_), "=v"(f2_), "=v"(f3_)                           \
      : "v"(fp_) : "memory");                                                \
    __builtin_amdgcn_sched_barrier(0);                                       \
    PFSTMT;                                                                  \
    __builtin_amdgcn_sched_barrier(0);                                       \
    asm volatile("s_waitcnt vmcnt(" NSTR ")" ::: "memory");                  \
    __builtin_amdgcn_sched_barrier(0);                                       \
    bool ok_ = (f0_ >= g) && (f1_ >= g) && (f2_ >= g) && (f3_ >= g);         \
    if (!__all(ok_)) slow_spin(g);                                           \
    asm volatile("" ::: "memory");                                           \
    __builtin_amdgcn_sched_barrier(0);                                       \
    ++g;                                                                     \
  } while (0)

__global__ void __launch_bounds__(NT, 1)
rwkv_persistent(Params p) {
  const int b    = blockIdx.x;
  const int t    = threadIdx.x;
  const int wid  = t >> 6;
  const int lane = t & 63;
  const int i0   = t * 4;

  __shared__ float lds[NFFN];
  __shared__ float part[8];

  float4 wr[20];   // weight prefetch (literal-indexed)
  float4 pr[6];    // param prefetch
  unsigned g = 1;

  const int rowq = b * 4 + wid;

  // ---- prefetch bundles (params first = oldest, then weights) ----
  auto pfA = [&](int L) {       // 6 + 12 = 18 vmem loads
    const int o = L * NEMBD + i0;
    pr[0] = *(const float4*)&p.ln1w[o];
    pr[1] = *(const float4*)&p.ln1b[o];
    pr[2] = *(const float4*)&p.state[0 * NLAYER * NEMBD + o];
    pr[3] = *(const float4*)&p.kktk[o];
    pr[4] = *(const float4*)&p.vvtv[o];
    pr[5] = *(const float4*)&p.rrtr[o];
    const float* W = p.key + (size_t)L * 3 * NEMBD * NEMBD
                   + (size_t)(b * 12 + wid * 3) * NEMBD + lane * 4;
#pragma unroll
    for (int r = 0; r < 3; ++r)
#pragma unroll
      for (int jj = 0; jj < 4; ++jj)
        wr[r * 4 + jj] = *(const float4*)&W[(size_t)r * NEMBD + jj * 256];
  };
  auto pfB = [&](int L) {       // 4 + 4 = 8
    const int o = L * NEMBD + i0;
    pr[0] = *(const float4*)&p.tf[o];
    pr[1] = *(const float4*)&p.state[1 * NLAYER * NEMBD + o];
    pr[2] = *(const float4*)&p.state[2 * NLAYER * NEMBD + o];
    pr[3] = *(const float4*)&p.td[o];
    const float* W = p.outputv + ((size_t)L * NEMBD + rowq) * NEMBD + lane * 4;
#pragma unroll
    for (int jj = 0; jj < 4; ++jj)
      wr[jj] = *(const float4*)&W[jj * 256];
  };
  int isk3[5], rid3[5], voff3[5];
#pragma unroll
  for (int sI = 0; sI < 5; ++sI) {
    int qI = wid * 5 + sI;
    if (qI < 16) { isk3[sI] = 1; rid3[sI] = b * 16 + qI;       voff3[sI] = 0; }
    else         { isk3[sI] = 0; rid3[sI] = b * 4 + (qI - 16); voff3[sI] = NEMBD; }
  }
  auto pfC = [&](int L) {       // 5 + 20 = 25
    const int o = L * NEMBD + i0;
    pr[0] = *(const float4*)&p.ln2w[o];
    pr[1] = *(const float4*)&p.ln2b[o];
    pr[2] = *(const float4*)&p.state[3 * NLAYER * NEMBD + o];
    pr[3] = *(const float4*)&p.tmk[o];
    pr[4] = *(const float4*)&p.tmr[o];
#pragma unroll
    for (int sI = 0; sI < 5; ++sI) {
      const float* wp = isk3[sI]
        ? p.kffn + ((size_t)L * NFFN  + rid3[sI]) * NEMBD
        : p.rffn + ((size_t)L * NEMBD + rid3[sI]) * NEMBD;
      wp += lane * 4;
#pragma unroll
      for (int jj = 0; jj < 4; ++jj)
        wr[sI * 4 + jj] = *(const float4*)&wp[jj * 256];
    }
  };
  auto pfD = [&](int L) {       // 16
    const float* W = p.vffn + ((size_t)L * NEMBD + rowq) * NFFN + lane * 4;
#pragma unroll
    for (int jj = 0; jj < 16; ++jj)
      wr[jj] = *(const float4*)&W[jj * 256];
  };
  auto slow_spin = [&](unsigned tgt) {
    long c = 0;
    for (;;) {
      bool mine = true;
#pragma unroll
      for (int j = 0; j < 4; ++j)
        mine &= (guload(&p.flags[(unsigned)(lane * 4 + j) * FLAG_STRIDE]) >= tgt);
      if (__all(mine)) break;
      __builtin_amdgcn_s_sleep(1);
      if (++c > (1L << 18)) break;   // safety valve: wrong beats hang
    }
  };

  pfA(0);   // layer-0 stage-1 params+weights; no barrier before stage 1

  for (int l = 0; l < NLAYER; ++l) {
    const bool w1 = (b == (l * 4 + 0) % NB);
    const bool w2 = (b == (l * 4 + 1) % NB);
    const bool w3 = (b == (l * 4 + 2) % NB);

    // ================= stage 1: ln1 + masks + k/v/r GEMV =================
    {
      float xa[4];
      if (l == 0) {
        float4 x4 = *(const float4*)&p.x[i0];
        xa[0] = x4.x; xa[1] = x4.y; xa[2] = x4.z; xa[3] = x4.w;
      } else {
#pragma unroll
        for (int j = 0; j < 4; ++j) xa[j] = gload(&p.xbuf[i0 + j]);
      }
      float s = xa[0] + xa[1] + xa[2] + xa[3];
      float q = xa[0]*xa[0] + xa[1]*xa[1] + xa[2]*xa[2] + xa[3]*xa[3];
      s = wred(s); q = wred(q);
      if (lane == 0) { part[wid] = s; part[4 + wid] = q; }
      lbar();
      float ts = part[0] + part[1] + part[2] + part[3];
      float tq = part[4] + part[5] + part[6] + part[7];
      float m  = ts * (1.f / NEMBD);
      float rs = rsqrtf(tq * (1.f / NEMBD) - m * m + LN_EPS);
#pragma unroll
      for (int j = 0; j < 4; ++j) {
        int i = i0 + j;
        float xy  = (xa[j] - m) * rs * fcomp(pr[0], j) + fcomp(pr[1], j);
        float sav = fcomp(pr[2], j);
        lds[i]             = xy + fcomp(pr[3], j) * sav;
        lds[NEMBD + i]     = xy + fcomp(pr[4], j) * sav;
        lds[2 * NEMBD + i] = xy + fcomp(pr[5], j) * sav;
        if (w1) p.out[OUT_SA + l * NEMBD + i] = xy;   // statea_new
      }
      lbar();
      const int r0 = b * 12 + wid * 3;
      const float* v0 = lds + ((r0 + 0) >> 10) * NEMBD;
      const float* v1 = lds + ((r0 + 1) >> 10) * NEMBD;
      const float* v2 = lds + ((r0 + 2) >> 10) * NEMBD;
      float a0 = 0.f, a1 = 0.f, a2 = 0.f;
#pragma unroll
      for (int jj = 0; jj < 4; ++jj) {
        int col = lane * 4 + jj * 256;
        a0 += dot4(wr[0 * 4 + jj], *(const float4*)&v0[col]);
        a1 += dot4(wr[1 * 4 + jj], *(const float4*)&v1[col]);
        a2 += dot4(wr[2 * 4 + jj], *(const float4*)&v2[col]);
      }
      a0 = wred(a0); a1 = wred(a1); a2 = wred(a2);
      if (lane == 0) {
        gstore(&p.kvr[r0 + 0], a0);
        gstore(&p.kvr[r0 + 1], a1);
        gstore(&p.kvr[r0 + 2], a2);
      }
    }
    bar_flag(p.flags, g);
    FASTPOLL("8", pfB(l));

    // ================= stage 2: wkv combine + outputv GEMV =================
    {
      float xc = (l == 0) ? p.x[rowq] : gload(&p.xbuf[rowq]);   // hoisted
      float kk[4], vv[4], rv[4];
#pragma unroll
      for (int j = 0; j < 4; ++j) {
        kk[j] = gload(&p.kvr[i0 + j]);
        vv[j] = gload(&p.kvr[NEMBD + i0 + j]);
        rv[j] = gload(&p.kvr[2 * NEMBD + i0 + j]);
      }
#pragma unroll
      for (int j = 0; j < 4; ++j) {
        float sb = fcomp(pr[1], j), sc = fcomp(pr[2], j);
        float etfk = expf(fcomp(pr[0], j) + kk[j]);
        float er   = expf(rv[j]);
        // sc*er + exp(tf+k+r) + sc + etfk == (sc+etfk)*(1+er)
        lds[i0 + j] = (sb + etfk * vv[j]) / ((sc + etfk) * (1.f + er));
        if (w2) {
          float ek = expf(kk[j]), ed = expf(fcomp(pr[3], j));
          p.out[OUT_SB + l * NEMBD + i0 + j] = sb * ed + ek * vv[j];
          p.out[OUT_SC + l * NEMBD + i0 + j] = sc * ed + ek;
        }
      }
      lbar();
      float acc = 0.f;
#pragma unroll
      for (int jj = 0; jj < 4; ++jj) {
        int col = lane * 4 + jj * 256;
        acc += dot4(wr[jj], *(const float4*)&lds[col]);
      }
      acc = wred(acc);
      if (lane == 0) gstore(&p.sxx[rowq], xc + acc);
    }
    bar_flag(p.flags, g);
    FASTPOLL("25", pfC(l));

    // ================= stage 3: ln2 + masks + kffn/rffn GEMV =================
    {
      float xa[4];
#pragma unroll
      for (int j = 0; j < 4; ++j) xa[j] = gload(&p.sxx[i0 + j]);
      float s = xa[0] + xa[1] + xa[2] + xa[3];
      float q = xa[0]*xa[0] + xa[1]*xa[1] + xa[2]*xa[2] + xa[3]*xa[3];
      s = wred(s); q = wred(q);
      if (lane == 0) { part[wid] = s; part[4 + wid] = q; }
      lbar();
      float ts = part[0] + part[1] + part[2] + part[3];
      float tq = part[4] + part[5] + part[6] + part[7];
      float m  = ts * (1.f / NEMBD);
      float rs = rsqrtf(tq * (1.f / NEMBD) - m * m + LN_EPS);
#pragma unroll
      for (int j = 0; j < 4; ++j) {
        int i = i0 + j;
        float xx  = (xa[j] - m) * rs * fcomp(pr[0], j) + fcomp(pr[1], j);
        float sdv = fcomp(pr[2], j);
        lds[i]         = xx + fcomp(pr[3], j) * sdv;
        lds[NEMBD + i] = xx + fcomp(pr[4], j) * sdv;
        if (w3) p.out[OUT_SD + l * NEMBD + i] = xx;   // stated_new
      }
      lbar();
      float acc[5] = {0.f, 0.f, 0.f, 0.f, 0.f};
#pragma unroll
      for (int jj = 0; jj < 4; ++jj) {
        int col = lane * 4 + jj * 256;
#pragma unroll
        for (int sI = 0; sI < 5; ++sI)
          acc[sI] += dot4(wr[sI * 4 + jj], *(const float4*)&lds[voff3[sI] + col]);
      }
#pragma unroll
      for (int sI = 0; sI < 5; ++sI) {
        float r = wred(acc[sI]);
        if (lane == 0) {
          if (isk3[sI]) { float kv = fmaxf(r, 0.f); gstore(&p.kfb[rid3[sI]], kv * kv); }
          else          { gstore(&p.rfb[rid3[sI]], expf(r)); }
        }
      }
    }
    bar_flag(p.flags, g);
    FASTPOLL("16", pfD(l));

    // ================= stage 4: vffn GEMV + x update =================
    {
      float sxxv = gload(&p.sxx[rowq]);   // hoisted (stable since stage-2 bar)
      float rfbv = gload(&p.rfb[rowq]);   // hoisted (stable since stage-3 bar)
#pragma unroll
      for (int pass = 0; pass < 4; ++pass) {
        int idx = pass * NEMBD + i0;
        float a0 = gload(&p.kfb[idx + 0]);
        float a1 = gload(&p.kfb[idx + 1]);
        float a2 = gload(&p.kfb[idx + 2]);
        float a3 = gload(&p.kfb[idx + 3]);
        *(float4*)&lds[idx] = make_float4(a0, a1, a2, a3);
      }
      lbar();
      float accA = 0.f, accB = 0.f;
#pragma unroll
      for (int jj = 0; jj < 16; jj += 2) {
        int col = lane * 4 + jj * 256;
        accA += dot4(wr[jj],     *(const float4*)&lds[col]);
        accB += dot4(wr[jj + 1], *(const float4*)&lds[col + 256]);
      }
      float acc = wred(accA + accB);
      if (lane == 0) {
        float xn = sxxv + acc / (rfbv + 1.f);
        if (l == NLAYER - 1) p.out[rowq] = xn;     // final x_out
        else                 gstore(&p.xbuf[rowq], xn);
      }
    }
    if (l < NLAYER - 1) {
      bar_flag(p.flags, g);
      FASTPOLL("18", pfA(l + 1));
    }
  }
}

__global__ void rwkv_init(unsigned* flags) {
  flags[threadIdx.x * FLAG_STRIDE] = 0u;
}

extern "C" void kernel_launch(void* const* d_in, const int* in_sizes, int n_in,
                              void* d_out, int out_size, void* d_ws, size_t ws_size,
                              hipStream_t stream) {
  Params p;
  p.x       = (const float*)d_in[0];
  p.state   = (const float*)d_in[1];
  p.ln1w    = (const float*)d_in[2];
  p.ln1b    = (const float*)d_in[3];
  p.ln2w    = (const float*)d_in[4];
  p.ln2b    = (const float*)d_in[5];
  p.td      = (const float*)d_in[6];
  p.tf      = (const float*)d_in[7];
  p.kktk    = (const float*)d_in[8];
  p.vvtv    = (const float*)d_in[9];
  p.rrtr    = (const float*)d_in[10];
  p.key     = (const float*)d_in[11];
  p.outputv = (const float*)d_in[12];
  p.tmk     = (const float*)d_in[13];
  p.tmr     = (const float*)d_in[14];
  p.kffn    = (const float*)d_in[15];
  p.rffn    = (const float*)d_in[16];
  p.vffn    = (const float*)d_in[17];
  p.out     = (float*)d_out;

  float* ws = (float*)d_ws;
  p.xbuf = ws;                       // [1024]
  p.kvr  = ws + NEMBD;               // [3*1024]
  p.sxx  = ws + 4 * NEMBD;           // [1024]
  p.rfb  = ws + 5 * NEMBD;           // [1024]
  p.kfb  = ws + 6 * NEMBD;           // [4096]   -> ends at byte 40960
  p.flags = (unsigned*)((char*)d_ws + 49152);   // 256 x 128B = 32 KiB

  rwkv_init<<<1, NB, 0, stream>>>(p.flags);
  rwkv_persistent<<<NB, NT, 0, stream>>>(p);
}

// Round 10
// 449.397 us; speedup vs baseline: 1.3013x; 1.3013x over previous
//
#include <hip/hip_runtime.h>
#include <math.h>
#include <stddef.h>

#define NLAYER 24
#define NEMBD  1024
#define NFFN   4096
#define NB     256
#define NT     256
#define LN_EPS 1e-5f

#define OUT_SA (NEMBD)
#define OUT_SB (NEMBD + NLAYER*NEMBD)
#define OUT_SC (NEMBD + 2*NLAYER*NEMBD)
#define OUT_SD (NEMBD + 3*NLAYER*NEMBD)

typedef unsigned long long u64;
typedef unsigned u32;

// packed-word queues in workspace (u64 each: tag<<32 | float bits)
#define QX_OFF    0        // 1024  x' per layer
#define QKVR_OFF  1024     // 3072  k,v,r
#define QSXX_OFF  4096     // 1024  sxx
#define QKFB_OFF  5120     // 4096  kf
#define QTOTAL    9216

struct Params {
  const float *x, *state, *ln1w, *ln1b, *ln2w, *ln2b, *td, *tf, *kktk, *vvtv, *rrtr;
  const float *key, *outputv, *tmk, *tmr, *kffn, *rffn, *vffn;
  float *out;
  u64 *q;
};

__device__ __forceinline__ float wred(float v) {
#pragma unroll
  for (int o = 32; o > 0; o >>= 1) v += __shfl_xor(v, o, 64);
  return v;
}
__device__ __forceinline__ float dot4(float4 a, float4 b) {
  return a.x*b.x + a.y*b.y + a.z*b.z + a.w*b.w;
}
__device__ __forceinline__ float fcomp(float4 v, int j) {   // literal j only
  return j == 0 ? v.x : (j == 1 ? v.y : (j == 2 ? v.z : v.w));
}
// relaxed agent-scope 8B ops -> sc0/sc1 global ops through the LLC (bypass
// the non-coherent XCD L2); single-instruction dwordx2 => value+tag atomic.
__device__ __forceinline__ u64 qload(const u64* a) {
  return __hip_atomic_load(a, __ATOMIC_RELAXED, __HIP_MEMORY_SCOPE_AGENT);
}
__device__ __forceinline__ void qput(u64* a, float v, u32 tag) {
  u64 w = ((u64)tag << 32) | (u64)__float_as_uint(v);
  __hip_atomic_store(a, w, __ATOMIC_RELAXED, __HIP_MEMORY_SCOPE_AGENT);
}
__device__ __forceinline__ u32   qtag(u64 w) { return (u32)(w >> 32); }
__device__ __forceinline__ float qval(u64 w) { return __uint_as_float((u32)w); }

// intra-block barrier: LDS ordering only; global prefetch stays in flight
__device__ __forceinline__ void lbar() {
  asm volatile("s_waitcnt lgkmcnt(0)" ::: "memory");
  __builtin_amdgcn_s_barrier();
  asm volatile("" ::: "memory");
}

__global__ void __launch_bounds__(NT, 1)
rwkv_persistent(Params p) {
  const int b    = blockIdx.x;
  const int t    = threadIdx.x;
  const int wid  = t >> 6;
  const int lane = t & 63;
  const int i0   = t * 4;
  const int rowq = b * 4 + wid;

  __shared__ float lds[NFFN];
  __shared__ float part[8];
  __shared__ float sxw[4];     // own sxx[rowq] per wave (stage2 -> stage4)
  __shared__ float rfw[4];     // own rfb[rowq]           (stage3 -> stage4)

  u64* QX   = p.q + QX_OFF;
  u64* QKVR = p.q + QKVR_OFF;
  u64* QSXX = p.q + QSXX_OFF;
  u64* QKFB = p.q + QKFB_OFF;

  float4 wr[20];   // weight prefetch registers (literal-indexed only)

  // ---- weight prefetch bundles ----
  auto pf1 = [&](int L) {      // key: 3 rows x 4 chunks
    const float* W = p.key + (size_t)L * 3 * NEMBD * NEMBD
                   + (size_t)(b * 12 + wid * 3) * NEMBD + lane * 4;
#pragma unroll
    for (int r = 0; r < 3; ++r)
#pragma unroll
      for (int jj = 0; jj < 4; ++jj)
        wr[r * 4 + jj] = *(const float4*)&W[(size_t)r * NEMBD + jj * 256];
  };
  auto pf2 = [&](int L) {      // outputv: 1 row x 4
    const float* W = p.outputv + ((size_t)L * NEMBD + rowq) * NEMBD + lane * 4;
#pragma unroll
    for (int jj = 0; jj < 4; ++jj)
      wr[jj] = *(const float4*)&W[jj * 256];
  };
  int isk3[5], rid3[5], voff3[5];
#pragma unroll
  for (int sI = 0; sI < 5; ++sI) {
    int qI = wid * 5 + sI;
    if (qI < 16) { isk3[sI] = 1; rid3[sI] = b * 16 + qI;       voff3[sI] = 0; }
    else         { isk3[sI] = 0; rid3[sI] = b * 4 + (qI - 16); voff3[sI] = NEMBD; }
  }
  auto pf3 = [&](int L) {      // kffn/rffn: 5 rows x 4
#pragma unroll
    for (int sI = 0; sI < 5; ++sI) {
      const float* wp = isk3[sI]
        ? p.kffn + ((size_t)L * NFFN  + rid3[sI]) * NEMBD
        : p.rffn + ((size_t)L * NEMBD + rid3[sI]) * NEMBD;
      wp += lane * 4;
#pragma unroll
      for (int jj = 0; jj < 4; ++jj)
        wr[sI * 4 + jj] = *(const float4*)&wp[jj * 256];
    }
  };
  auto pf4 = [&](int L) {      // vffn: 1 row x 16
    const float* W = p.vffn + ((size_t)L * NEMBD + rowq) * NFFN + lane * 4;
#pragma unroll
    for (int jj = 0; jj < 16; ++jj)
      wr[jj] = *(const float4*)&W[jj * 256];
  };

  pf1(0);   // layer-0 stage-1 weights in flight from the start

  for (int l = 0; l < NLAYER; ++l) {
    const u32 t1 = (u32)(4 * l + 1), t2 = t1 + 1, t3 = t1 + 2, t4 = t1 + 3;
    const bool w1 = (b == (l * 4 + 0) % NB);
    const bool w2 = (b == (l * 4 + 1) % NB);
    const bool w3 = (b == (l * 4 + 2) % NB);

    // ================= stage 1: poll x -> ln1 -> masks -> k/v/r GEMV ======
    {
      float xa[4];
      if (l == 0) {
        float4 x4 = *(const float4*)&p.x[i0];
        xa[0] = x4.x; xa[1] = x4.y; xa[2] = x4.z; xa[3] = x4.w;
      } else {
        const u32 tp = (u32)(4 * l);   // prev layer stage-4 tag
        u64 a0, a1, a2, a3; long c = 0;
        for (;;) {
          a0 = qload(&QX[i0 + 0]); a1 = qload(&QX[i0 + 1]);
          a2 = qload(&QX[i0 + 2]); a3 = qload(&QX[i0 + 3]);
          if (qtag(a0) >= tp && qtag(a1) >= tp && qtag(a2) >= tp && qtag(a3) >= tp) break;
          __builtin_amdgcn_s_sleep(1);
          if (++c > (1L << 20)) break;   // safety valve: wrong beats hang
        }
        xa[0] = qval(a0); xa[1] = qval(a1); xa[2] = qval(a2); xa[3] = qval(a3);
      }
      float s = xa[0] + xa[1] + xa[2] + xa[3];
      float q = xa[0]*xa[0] + xa[1]*xa[1] + xa[2]*xa[2] + xa[3]*xa[3];
      s = wred(s); q = wred(q);
      if (lane == 0) { part[wid] = s; part[4 + wid] = q; }
      lbar();
      float m  = (part[0] + part[1] + part[2] + part[3]) * (1.f / NEMBD);
      float tq = (part[4] + part[5] + part[6] + part[7]) * (1.f / NEMBD);
      float rs = rsqrtf(tq - m * m + LN_EPS);
      const int o = l * NEMBD + i0;
      float4 l1w = *(const float4*)&p.ln1w[o];
      float4 l1b = *(const float4*)&p.ln1b[o];
      float4 sa  = *(const float4*)&p.state[0 * NLAYER * NEMBD + o];
      float4 kk  = *(const float4*)&p.kktk[o];
      float4 vv  = *(const float4*)&p.vvtv[o];
      float4 rr  = *(const float4*)&p.rrtr[o];
#pragma unroll
      for (int j = 0; j < 4; ++j) {
        int i = i0 + j;
        float xy  = (xa[j] - m) * rs * fcomp(l1w, j) + fcomp(l1b, j);
        float sav = fcomp(sa, j);
        lds[i]             = xy + fcomp(kk, j) * sav;
        lds[NEMBD + i]     = xy + fcomp(vv, j) * sav;
        lds[2 * NEMBD + i] = xy + fcomp(rr, j) * sav;
        if (w1) p.out[OUT_SA + l * NEMBD + i] = xy;   // statea_new
      }
      lbar();
      const int r0 = b * 12 + wid * 3;
      const float* v0 = lds + ((r0 + 0) >> 10) * NEMBD;
      const float* v1 = lds + ((r0 + 1) >> 10) * NEMBD;
      const float* v2 = lds + ((r0 + 2) >> 10) * NEMBD;
      float a0 = 0.f, a1 = 0.f, a2 = 0.f;
#pragma unroll
      for (int jj = 0; jj < 4; ++jj) {
        int col = lane * 4 + jj * 256;
        a0 += dot4(wr[0 * 4 + jj], *(const float4*)&v0[col]);
        a1 += dot4(wr[1 * 4 + jj], *(const float4*)&v1[col]);
        a2 += dot4(wr[2 * 4 + jj], *(const float4*)&v2[col]);
      }
      a0 = wred(a0); a1 = wred(a1); a2 = wred(a2);
      if (lane == 0) {              // the stores ARE the sync signal
        qput(&QKVR[r0 + 0], a0, t1);
        qput(&QKVR[r0 + 1], a1, t1);
        qput(&QKVR[r0 + 2], a2, t1);
      }
      pf2(l);                       // streams through stage tail + next poll
      lbar();
    }

    // ================= stage 2: poll kvr -> wkv -> outputv GEMV ==========
    {
      float kk[4], vv[4], rv[4];
      {
        u64 wk[4], wv[4], wq[4]; long c = 0;
        for (;;) {
          bool ok = true;
#pragma unroll
          for (int j = 0; j < 4; ++j) {
            wk[j] = qload(&QKVR[i0 + j]);
            wv[j] = qload(&QKVR[NEMBD + i0 + j]);
            wq[j] = qload(&QKVR[2 * NEMBD + i0 + j]);
            ok &= (qtag(wk[j]) >= t1) & (qtag(wv[j]) >= t1) & (qtag(wq[j]) >= t1);
          }
          if (ok) break;
          __builtin_amdgcn_s_sleep(1);
          if (++c > (1L << 20)) break;
        }
#pragma unroll
        for (int j = 0; j < 4; ++j) { kk[j] = qval(wk[j]); vv[j] = qval(wv[j]); rv[j] = qval(wq[j]); }
      }
      float xc;
      if (l == 0) xc = p.x[rowq];
      else {
        const u32 tp = (u32)(4 * l);
        u64 wx; long c = 0;
        for (;;) {
          wx = qload(&QX[rowq]);
          if (qtag(wx) >= tp) break;
          __builtin_amdgcn_s_sleep(1);
          if (++c > (1L << 20)) break;
        }
        xc = qval(wx);
      }
      const int o = l * NEMBD + i0;
      float4 tf = *(const float4*)&p.tf[o];
      float4 sb4 = *(const float4*)&p.state[1 * NLAYER * NEMBD + o];
      float4 sc4 = *(const float4*)&p.state[2 * NLAYER * NEMBD + o];
      float4 td4 = *(const float4*)&p.td[o];
#pragma unroll
      for (int j = 0; j < 4; ++j) {
        float sb = fcomp(sb4, j), sc = fcomp(sc4, j);
        float etfk = expf(fcomp(tf, j) + kk[j]);
        float er   = expf(rv[j]);
        // sc*er + exp(tf+k+r) + sc + etfk == (sc+etfk)*(1+er)
        lds[i0 + j] = (sb + etfk * vv[j]) / ((sc + etfk) * (1.f + er));
        if (w2) {
          float ek = expf(kk[j]), ed = expf(fcomp(td4, j));
          p.out[OUT_SB + l * NEMBD + i0 + j] = sb * ed + ek * vv[j];
          p.out[OUT_SC + l * NEMBD + i0 + j] = sc * ed + ek;
        }
      }
      lbar();
      float acc = 0.f;
#pragma unroll
      for (int jj = 0; jj < 4; ++jj) {
        int col = lane * 4 + jj * 256;
        acc += dot4(wr[jj], *(const float4*)&lds[col]);
      }
      acc = wred(acc);
      if (lane == 0) {
        float sxx = xc + acc;
        qput(&QSXX[rowq], sxx, t2);
        sxw[wid] = sxx;             // own copy for stage 4 (no round trip)
      }
      pf3(l);
      lbar();
    }

    // ================= stage 3: poll sxx -> ln2 -> kffn/rffn GEMV ========
    {
      float xa[4];
      {
        u64 a0, a1, a2, a3; long c = 0;
        for (;;) {
          a0 = qload(&QSXX[i0 + 0]); a1 = qload(&QSXX[i0 + 1]);
          a2 = qload(&QSXX[i0 + 2]); a3 = qload(&QSXX[i0 + 3]);
          if (qtag(a0) >= t2 && qtag(a1) >= t2 && qtag(a2) >= t2 && qtag(a3) >= t2) break;
          __builtin_amdgcn_s_sleep(1);
          if (++c > (1L << 20)) break;
        }
        xa[0] = qval(a0); xa[1] = qval(a1); xa[2] = qval(a2); xa[3] = qval(a3);
      }
      float s = xa[0] + xa[1] + xa[2] + xa[3];
      float q = xa[0]*xa[0] + xa[1]*xa[1] + xa[2]*xa[2] + xa[3]*xa[3];
      s = wred(s); q = wred(q);
      if (lane == 0) { part[wid] = s; part[4 + wid] = q; }
      lbar();
      float m  = (part[0] + part[1] + part[2] + part[3]) * (1.f / NEMBD);
      float tq = (part[4] + part[5] + part[6] + part[7]) * (1.f / NEMBD);
      float rs = rsqrtf(tq - m * m + LN_EPS);
      const int o = l * NEMBD + i0;
      float4 l2w = *(const float4*)&p.ln2w[o];
      float4 l2b = *(const float4*)&p.ln2b[o];
      float4 sd4 = *(const float4*)&p.state[3 * NLAYER * NEMBD + o];
      float4 tmk = *(const float4*)&p.tmk[o];
      float4 tmr = *(const float4*)&p.tmr[o];
#pragma unroll
      for (int j = 0; j < 4; ++j) {
        int i = i0 + j;
        float xx  = (xa[j] - m) * rs * fcomp(l2w, j) + fcomp(l2b, j);
        float sdv = fcomp(sd4, j);
        lds[i]         = xx + fcomp(tmk, j) * sdv;
        lds[NEMBD + i] = xx + fcomp(tmr, j) * sdv;
        if (w3) p.out[OUT_SD + l * NEMBD + i] = xx;   // stated_new
      }
      lbar();
      float acc[5] = {0.f, 0.f, 0.f, 0.f, 0.f};
#pragma unroll
      for (int jj = 0; jj < 4; ++jj) {
        int col = lane * 4 + jj * 256;
#pragma unroll
        for (int sI = 0; sI < 5; ++sI)
          acc[sI] += dot4(wr[sI * 4 + jj], *(const float4*)&lds[voff3[sI] + col]);
      }
#pragma unroll
      for (int sI = 0; sI < 5; ++sI) {
        float r = wred(acc[sI]);
        if (lane == 0) {
          if (isk3[sI]) { float kv = fmaxf(r, 0.f); qput(&QKFB[rid3[sI]], kv * kv, t3); }
          else          { rfw[rid3[sI] - b * 4] = expf(r); }   // own-only: LDS
        }
      }
      pf4(l);
      lbar();
    }

    // ================= stage 4: poll kf -> vffn GEMV -> x' ===============
    {
      {
        u64 w[16]; long c = 0;
        for (;;) {
          bool ok = true;
#pragma unroll
          for (int pass = 0; pass < 4; ++pass)
#pragma unroll
            for (int j = 0; j < 4; ++j) {
              w[pass * 4 + j] = qload(&QKFB[pass * NEMBD + i0 + j]);
              ok &= (qtag(w[pass * 4 + j]) >= t3);
            }
          if (ok) break;
          __builtin_amdgcn_s_sleep(1);
          if (++c > (1L << 20)) break;
        }
#pragma unroll
        for (int pass = 0; pass < 4; ++pass)
#pragma unroll
          for (int j = 0; j < 4; ++j)
            lds[pass * NEMBD + i0 + j] = qval(w[pass * 4 + j]);
      }
      lbar();
      float accA = 0.f, accB = 0.f;
#pragma unroll
      for (int jj = 0; jj < 16; jj += 2) {
        int col = lane * 4 + jj * 256;
        accA += dot4(wr[jj],     *(const float4*)&lds[col]);
        accB += dot4(wr[jj + 1], *(const float4*)&lds[col + 256]);
      }
      float acc = wred(accA + accB);
      if (lane == 0) {
        float xn = sxw[wid] + acc / (rfw[wid] + 1.f);
        if (l == NLAYER - 1) p.out[rowq] = xn;         // final x_out
        else                 qput(&QX[rowq], xn, t4);
      }
      if (l < NLAYER - 1) pf1(l + 1);
      lbar();
    }
  }
}

__global__ void rwkv_init(u64* q) {
  // zero all tags (36 words per thread x 256 threads = 9216)
  for (int i = 0; i < 36; ++i)
    q[threadIdx.x * 36 + i] = 0ull;
}

extern "C" void kernel_launch(void* const* d_in, const int* in_sizes, int n_in,
                              void* d_out, int out_size, void* d_ws, size_t ws_size,
                              hipStream_t stream) {
  Params p;
  p.x       = (const float*)d_in[0];
  p.state   = (const float*)d_in[1];
  p.ln1w    = (const float*)d_in[2];
  p.ln1b    = (const float*)d_in[3];
  p.ln2w    = (const float*)d_in[4];
  p.ln2b    = (const float*)d_in[5];
  p.td      = (const float*)d_in[6];
  p.tf      = (const float*)d_in[7];
  p.kktk    = (const float*)d_in[8];
  p.vvtv    = (const float*)d_in[9];
  p.rrtr    = (const float*)d_in[10];
  p.key     = (const float*)d_in[11];
  p.outputv = (const float*)d_in[12];
  p.tmk     = (const float*)d_in[13];
  p.tmr     = (const float*)d_in[14];
  p.kffn    = (const float*)d_in[15];
  p.rffn    = (const float*)d_in[16];
  p.vffn    = (const float*)d_in[17];
  p.out     = (float*)d_out;
  p.q       = (u64*)d_ws;             // 9216 u64 = 73728 B

  rwkv_init<<<1, NB, 0, stream>>>(p.q);
  rwkv_persistent<<<NB, NT, 0, stream>>>(p);
}